// Round 1
// baseline (1288.493 us; speedup 1.0000x reference)
//
#include <hip/hip_runtime.h>

typedef __attribute__((ext_vector_type(8))) short short8;
typedef __attribute__((ext_vector_type(4))) float floatx4;

__device__ __forceinline__ unsigned short f2bf(float f) {
  union { float f; unsigned int u; } un; un.f = f;
  unsigned int r = un.u + 0x7FFFu + ((un.u >> 16) & 1u);
  return (unsigned short)(r >> 16);
}
__device__ __forceinline__ float bf2f(unsigned short h) {
  union { unsigned int u; float f; } un; un.u = ((unsigned int)h) << 16;
  return un.f;
}

__device__ __forceinline__ void async_ld16(const unsigned short* g, unsigned short* l) {
  __builtin_amdgcn_global_load_lds(
      (const __attribute__((address_space(1))) void*)g,
      (__attribute__((address_space(3))) void*)l, 16, 0, 0);
}

// ---------------------------------------------------------------------------
// GEMM: C[M,N] = A[M,K](bf16,row-major) @ W[N,K](bf16,row-major)^T + bias
//       (+ res fp32, optional relu). Out fp32 or bf16.
// Tiles: 128x128, BK=64, 256 threads (4 waves, 2x2 of 64x64), mfma 16x16x32.
// LDS XOR swizzle: slot (r, cb') holds global colblock cb = cb' ^ (r&7);
// staging order stays lane-linear (global_load_lds requirement), fragment
// reads become 2-way (free) instead of 16-way conflicted.
// ---------------------------------------------------------------------------
template<int OUT_BF16, int RELU>
__global__ __launch_bounds__(256, 2)
void gemm_bt(const unsigned short* __restrict__ A, const unsigned short* __restrict__ B,
             const float* __restrict__ bias, const float* __restrict__ res,
             void* __restrict__ Cout, int M, int N, int K) {
  __shared__ __align__(16) unsigned short sA[128 * 64];
  __shared__ __align__(16) unsigned short sB[128 * 64];
  const int tid  = threadIdx.x;
  const int lane = tid & 63;
  const int wave = tid >> 6;
  const int m0 = blockIdx.y * 128;
  const int n0 = blockIdx.x * 128;

  floatx4 acc[4][4];
#pragma unroll
  for (int i = 0; i < 4; i++)
#pragma unroll
    for (int j = 0; j < 4; j++) acc[i][j] = (floatx4){0.f, 0.f, 0.f, 0.f};

  int s_r[4], s_gc[4], s_lb[4];
#pragma unroll
  for (int it = 0; it < 4; it++) {
    int e = it * 2048 + tid * 8;
    int r = e >> 6;
    int cb = (e >> 3) & 7;
    s_r[it]  = r;
    s_gc[it] = (cb ^ (r & 7)) * 8;
    s_lb[it] = it * 2048 + wave * 512;  // wave-uniform LDS base (elements)
  }

  const int nkt = K >> 6;
  const int wm = (wave >> 1) * 64;
  const int wn = (wave & 1) * 64;
  const int fr = lane & 15;
  const int q  = lane >> 4;

  for (int kt = 0; kt < nkt; kt++) {
    const int k0 = kt << 6;
#pragma unroll
    for (int it = 0; it < 4; it++) {
      async_ld16(A + (size_t)(m0 + s_r[it]) * K + k0 + s_gc[it], &sA[s_lb[it]]);
      async_ld16(B + (size_t)(n0 + s_r[it]) * K + k0 + s_gc[it], &sB[s_lb[it]]);
    }
    __syncthreads();
#pragma unroll
    for (int kk = 0; kk < 64; kk += 32) {
      short8 af[4], bfr[4];
#pragma unroll
      for (int t = 0; t < 4; t++) {
        int ra = wm + t * 16 + fr;
        int cba = (kk >> 3) + q;
        af[t] = *(const short8*)&sA[ra * 64 + ((cba ^ (ra & 7)) * 8)];
        int rb = wn + t * 16 + fr;
        bfr[t] = *(const short8*)&sB[rb * 64 + ((cba ^ (rb & 7)) * 8)];
      }
#pragma unroll
      for (int i = 0; i < 4; i++)
#pragma unroll
        for (int j = 0; j < 4; j++)
          acc[i][j] = __builtin_amdgcn_mfma_f32_16x16x32_bf16(af[i], bfr[j], acc[i][j], 0, 0, 0);
    }
    __syncthreads();
  }

  // epilogue: C/D layout col=lane&15, row=(lane>>4)*4+reg
#pragma unroll
  for (int i = 0; i < 4; i++) {
#pragma unroll
    for (int j = 0; j < 4; j++) {
#pragma unroll
      for (int rg = 0; rg < 4; rg++) {
        int row = m0 + wm + i * 16 + q * 4 + rg;
        int col = n0 + wn + j * 16 + fr;
        float v = acc[i][j][rg];
        if (bias) v += bias[col];
        if (res)  v += res[(size_t)row * N + col];
        if (RELU) v = v > 0.f ? v : 0.f;
        if (OUT_BF16) ((unsigned short*)Cout)[(size_t)row * N + col] = f2bf(v);
        else          ((float*)Cout)[(size_t)row * N + col] = v;
      }
    }
  }
}

// ---------------------------------------------------------------------------
// Embedding gather: x[p,e] = W_in[e, caps[p]] + b_in[e] + pos_emb[p%80, e]
// ---------------------------------------------------------------------------
__global__ __launch_bounds__(512)
void embed_kernel(const int* __restrict__ caps, const float* __restrict__ W_in,
                  const float* __restrict__ b_in, const float* __restrict__ pos,
                  float* __restrict__ x, unsigned short* __restrict__ xbf) {
  int pidx = blockIdx.x;
  int l = pidx % 80;
  int tok = caps[pidx];
  int e = threadIdx.x;
  float v = W_in[(size_t)e * 32000 + tok] + b_in[e] + pos[l * 512 + e];
  x[(size_t)pidx * 512 + e] = v;
  xbf[(size_t)pidx * 512 + e] = f2bf(v);
}

// ---------------------------------------------------------------------------
// LayerNorm over E=512; one wave per row. Optionally adds addvec (cross-attn
// constant). Writes fp32 (residual stream) + bf16 (GEMM A-operand).
// ---------------------------------------------------------------------------
__global__ __launch_bounds__(256)
void ln_kernel(const float* __restrict__ in, const float* __restrict__ addvec,
               const float* __restrict__ w, const float* __restrict__ b,
               float* __restrict__ xout, unsigned short* __restrict__ xbf) {
  int row = blockIdx.x * 4 + (threadIdx.x >> 6);
  int lane = threadIdx.x & 63;
  const float* p = in + (size_t)row * 512;
  float vals[8];
  float s = 0.f, s2 = 0.f;
#pragma unroll
  for (int j = 0; j < 8; j++) {
    float t = p[lane + j * 64];
    if (addvec) t += addvec[lane + j * 64];
    vals[j] = t; s += t; s2 += t * t;
  }
#pragma unroll
  for (int off = 32; off; off >>= 1) { s += __shfl_xor(s, off); s2 += __shfl_xor(s2, off); }
  float mean = s * (1.f / 512.f);
  float var = s2 * (1.f / 512.f) - mean * mean;
  float inv = rsqrtf(var + 1e-5f);
#pragma unroll
  for (int j = 0; j < 8; j++) {
    int c = lane + j * 64;
    float y = (vals[j] - mean) * inv * w[c] + b[c];
    xout[(size_t)row * 512 + c] = y;
    xbf[(size_t)row * 512 + c] = f2bf(y);
  }
}

// ---------------------------------------------------------------------------
// Self-attention, one block per (batch, head). L=80, hd=64. fp32 softmax.
// Register-tiled 5x5 / 5x4 outer products to cut LDS traffic.
// ---------------------------------------------------------------------------
__global__ __launch_bounds__(256)
void attn_kernel(const unsigned short* __restrict__ qkv, unsigned short* __restrict__ o) {
  __shared__ unsigned short sq[80][66], sk[80][66], sv[80][66];
  __shared__ float ss[80][81];
  const int tid = threadIdx.x;
  const int bb = blockIdx.x >> 3, hh = blockIdx.x & 7;
  const unsigned short* base = qkv + (size_t)bb * 80 * 1536 + hh * 64;
  for (int idx = tid; idx < 5120; idx += 256) {
    int r = idx >> 6, c = idx & 63;
    sq[r][c] = base[r * 1536 + c];
    sk[r][c] = base[r * 1536 + 512 + c];
    sv[r][c] = base[r * 1536 + 1024 + c];
  }
  __syncthreads();
  {
    const int ti = tid >> 4, tj = tid & 15;
    float acc[5][5];
#pragma unroll
    for (int a = 0; a < 5; a++)
#pragma unroll
      for (int b2 = 0; b2 < 5; b2++) acc[a][b2] = 0.f;
    for (int c = 0; c < 64; c++) {
      float qa[5], kb[5];
#pragma unroll
      for (int a = 0; a < 5; a++) qa[a] = bf2f(sq[ti + a * 16][c]);
#pragma unroll
      for (int b2 = 0; b2 < 5; b2++) kb[b2] = bf2f(sk[tj + b2 * 16][c]);
#pragma unroll
      for (int a = 0; a < 5; a++)
#pragma unroll
        for (int b2 = 0; b2 < 5; b2++) acc[a][b2] += qa[a] * kb[b2];
    }
#pragma unroll
    for (int a = 0; a < 5; a++)
#pragma unroll
      for (int b2 = 0; b2 < 5; b2++) {
        int i = ti + a * 16, j = tj + b2 * 16;
        ss[i][j] = (j <= i) ? acc[a][b2] * 0.125f : -1e30f;
      }
  }
  __syncthreads();
  if (tid < 80) {
    float mx = -1e30f;
    for (int j = 0; j < 80; j++) mx = fmaxf(mx, ss[tid][j]);
    float sum = 0.f;
    for (int j = 0; j < 80; j++) { float e2 = __expf(ss[tid][j] - mx); ss[tid][j] = e2; sum += e2; }
    float inv = 1.f / sum;
    for (int j = 0; j < 80; j++) ss[tid][j] *= inv;
  }
  __syncthreads();
  {
    const int ti = tid >> 4, td = tid & 15;
    float acc[5][4];
#pragma unroll
    for (int a = 0; a < 5; a++)
#pragma unroll
      for (int b2 = 0; b2 < 4; b2++) acc[a][b2] = 0.f;
    for (int j = 0; j < 80; j++) {
      float pa[5], vb[4];
#pragma unroll
      for (int a = 0; a < 5; a++) pa[a] = ss[ti + a * 16][j];
#pragma unroll
      for (int b2 = 0; b2 < 4; b2++) vb[b2] = bf2f(sv[j][td + b2 * 16]);
#pragma unroll
      for (int a = 0; a < 5; a++)
#pragma unroll
        for (int b2 = 0; b2 < 4; b2++) acc[a][b2] += pa[a] * vb[b2];
    }
#pragma unroll
    for (int a = 0; a < 5; a++)
#pragma unroll
      for (int b2 = 0; b2 < 4; b2++) {
        int i = ti + a * 16, d = td + b2 * 16;
        o[((size_t)bb * 80 + i) * 512 + hh * 64 + d] = f2bf(acc[a][b2]);
      }
  }
}

// ---------------------------------------------------------------------------
// Cross-attention constant: cav[e] = ca_out_b[e] + sum_f ca_out_w[e,f]*ca_in_b[2E+f]
// (memory is all-zero => K,V are biases; softmax over 1 key => weight 1)
// ---------------------------------------------------------------------------
__global__ __launch_bounds__(256)
void cavec_kernel(const float* __restrict__ w, const float* __restrict__ inb,
                  const float* __restrict__ ob, float* __restrict__ out) {
  int e = blockIdx.x * 4 + (threadIdx.x >> 6);
  int lane = threadIdx.x & 63;
  const float* row = w + (size_t)e * 512;
  float s = 0.f;
#pragma unroll
  for (int j = 0; j < 8; j++) s += row[lane + j * 64] * inb[1024 + lane + j * 64];
#pragma unroll
  for (int off = 32; off; off >>= 1) s += __shfl_xor(s, off);
  if (lane == 0) out[e] = s + ob[e];
}

// ---------------------------------------------------------------------------
// fp32 -> bf16 bulk convert (vectorized x4)
// ---------------------------------------------------------------------------
__global__ __launch_bounds__(256)
void convert_f2bf(const float* __restrict__ in, unsigned short* __restrict__ out, int n4) {
  int i = blockIdx.x * 256 + threadIdx.x;
  if (i < n4) {
    float4 v = ((const float4*)in)[i];
    ushort4 r;
    r.x = f2bf(v.x); r.y = f2bf(v.y); r.z = f2bf(v.z); r.w = f2bf(v.w);
    ((ushort4*)out)[i] = r;
  }
}

extern "C" void kernel_launch(void* const* d_in, const int* in_sizes, int n_in,
                              void* d_out, int out_size, void* d_ws, size_t ws_size,
                              hipStream_t stream) {
  const int*   caps     = (const int*)d_in[0];
  const float* W_in     = (const float*)d_in[1];
  const float* b_in     = (const float*)d_in[2];
  const float* pos_emb  = (const float*)d_in[3];
  const float* sa_in_w  = (const float*)d_in[4];
  const float* sa_in_b  = (const float*)d_in[5];
  const float* sa_out_w = (const float*)d_in[6];
  const float* sa_out_b = (const float*)d_in[7];
  const float* ca_in_b  = (const float*)d_in[9];
  const float* ca_out_w = (const float*)d_in[10];
  const float* ca_out_b = (const float*)d_in[11];
  const float* ff1_w    = (const float*)d_in[12];
  const float* ff1_b    = (const float*)d_in[13];
  const float* ff2_w    = (const float*)d_in[14];
  const float* ff2_b    = (const float*)d_in[15];
  const float* ln1_w    = (const float*)d_in[16];
  const float* ln1_b    = (const float*)d_in[17];
  const float* ln2_w    = (const float*)d_in[18];
  const float* ln2_b    = (const float*)d_in[19];
  const float* ln3_w    = (const float*)d_in[20];
  const float* ln3_b    = (const float*)d_in[21];
  const float* out_w    = (const float*)d_in[22];
  const float* out_b    = (const float*)d_in[23];

  char* ws = (char*)d_ws;
  size_t off = 0;
  auto alloc = [&](size_t bytes) {
    void* p = ws + off;
    off += (bytes + 255) & ~(size_t)255;
    return p;
  };
  unsigned short* w_sa_in  = (unsigned short*)alloc((size_t)4 * 1536 * 512 * 2);
  unsigned short* w_sa_out = (unsigned short*)alloc((size_t)4 * 512 * 512 * 2);
  unsigned short* w_ff1    = (unsigned short*)alloc((size_t)4 * 2048 * 512 * 2);
  unsigned short* w_ff2    = (unsigned short*)alloc((size_t)4 * 512 * 2048 * 2);
  unsigned short* w_out    = (unsigned short*)alloc((size_t)32000 * 512 * 2);
  float*          x        = (float*)alloc((size_t)2560 * 512 * 4);
  unsigned short* xbf      = (unsigned short*)alloc((size_t)2560 * 512 * 2);
  float*          t        = (float*)alloc((size_t)2560 * 512 * 4);
  unsigned short* qkv      = (unsigned short*)alloc((size_t)2560 * 1536 * 2);
  unsigned short* obf      = (unsigned short*)alloc((size_t)2560 * 512 * 2);
  unsigned short* hbf      = (unsigned short*)alloc((size_t)2560 * 2048 * 2);
  float*          cav      = (float*)alloc((size_t)512 * 4);

  // weight conversion fp32 -> bf16 (once per call; same work every call)
  convert_f2bf<<<(786432 + 255) / 256, 256, 0, stream>>>(sa_in_w, w_sa_in, 786432);
  convert_f2bf<<<(262144 + 255) / 256, 256, 0, stream>>>(sa_out_w, w_sa_out, 262144);
  convert_f2bf<<<(1048576 + 255) / 256, 256, 0, stream>>>(ff1_w, w_ff1, 1048576);
  convert_f2bf<<<(1048576 + 255) / 256, 256, 0, stream>>>(ff2_w, w_ff2, 1048576);
  convert_f2bf<<<(4096000 + 255) / 256, 256, 0, stream>>>(out_w, w_out, 4096000);

  embed_kernel<<<2560, 512, 0, stream>>>(caps, W_in, b_in, pos_emb, x, xbf);

  for (int i = 0; i < 4; i++) {
    // QKV projection: [2560,512] @ [512,1536]^T(-layout) -> bf16
    gemm_bt<1, 0><<<dim3(12, 20), 256, 0, stream>>>(
        xbf, w_sa_in + (size_t)i * 1536 * 512, sa_in_b + i * 1536, nullptr,
        qkv, 2560, 1536, 512);
    attn_kernel<<<256, 256, 0, stream>>>(qkv, obf);
    // out projection + residual (fp32)
    gemm_bt<0, 0><<<dim3(4, 20), 256, 0, stream>>>(
        obf, w_sa_out + (size_t)i * 512 * 512, sa_out_b + i * 512, x,
        t, 2560, 512, 512);
    ln_kernel<<<640, 256, 0, stream>>>(t, nullptr, ln1_w + i * 512, ln1_b + i * 512, x, xbf);
    // cross-attn constant + LN2 (in-place on x)
    cavec_kernel<<<128, 256, 0, stream>>>(
        ca_out_w + (size_t)i * 512 * 512, ca_in_b + (size_t)i * 1536, ca_out_b + i * 512, cav);
    ln_kernel<<<640, 256, 0, stream>>>(x, cav, ln2_w + i * 512, ln2_b + i * 512, x, xbf);
    // FFN
    gemm_bt<1, 1><<<dim3(16, 20), 256, 0, stream>>>(
        xbf, w_ff1 + (size_t)i * 2048 * 512, ff1_b + i * 2048, nullptr,
        hbf, 2560, 2048, 512);
    gemm_bt<0, 0><<<dim3(4, 20), 256, 0, stream>>>(
        hbf, w_ff2 + (size_t)i * 512 * 2048, ff2_b + i * 512, x,
        t, 2560, 512, 2048);
    ln_kernel<<<640, 256, 0, stream>>>(t, nullptr, ln3_w + i * 512, ln3_b + i * 512, x, xbf);
  }

  // final logits: [2560,512] @ [512,32000]^T(-layout) -> fp32 d_out
  gemm_bt<0, 0><<<dim3(250, 20), 256, 0, stream>>>(
      xbf, w_out, out_b, nullptr, (float*)d_out, 2560, 32000, 512);
}

// Round 2
// 1120.642 us; speedup vs baseline: 1.1498x; 1.1498x over previous
//
#include <hip/hip_runtime.h>

typedef __attribute__((ext_vector_type(8))) short short8;
typedef __attribute__((ext_vector_type(4))) float floatx4;

__device__ __forceinline__ unsigned short f2bf(float f) {
  union { float f; unsigned int u; } un; un.f = f;
  unsigned int r = un.u + 0x7FFFu + ((un.u >> 16) & 1u);
  return (unsigned short)(r >> 16);
}
__device__ __forceinline__ float bf2f(unsigned short h) {
  union { unsigned int u; float f; } un; un.u = ((unsigned int)h) << 16;
  return un.f;
}

__device__ __forceinline__ void async_ld16(const unsigned short* g, unsigned short* l) {
  __builtin_amdgcn_global_load_lds(
      (const __attribute__((address_space(1))) void*)g,
      (__attribute__((address_space(3))) void*)l, 16, 0, 0);
}

// ---------------------------------------------------------------------------
// GEMM: C[M,N] = A[M,K](bf16 rm) @ W[N,K](bf16 rm)^T + bias (+res fp32, relu).
// Template TM/TN in {128,64}. BK=64, 256 thr (4 waves 2x2), mfma 16x16x32,
// double-buffered LDS: stage(kt+1) issued right after the barrier that
// consumed stage(kt) -> global latency overlapped with a full compute phase.
// One barrier per kt. Global-side XOR swizzle keeps frag ds_read_b128 at the
// balanced 8-phase minimum. blockIdx.x = M-tile (fast) for B-tile L2 reuse.
// ---------------------------------------------------------------------------
template<int TM, int TN, int OUT_BF16, int RELU>
__global__ __launch_bounds__(256, (TM == 64) ? 4 : 2)
void gemm_bt(const unsigned short* __restrict__ A, const unsigned short* __restrict__ B,
             const float* __restrict__ bias, const float* __restrict__ res,
             void* __restrict__ Cout, int M, int N, int K) {
  constexpr int AELEM = TM * 64;
  constexpr int BELEM = TN * 64;
  constexpr int AIT = AELEM / 2048;
  constexpr int BIT = BELEM / 2048;
  constexpr int FM = TM / 32;
  constexpr int FN = TN / 32;
  __shared__ __align__(16) unsigned short sA[2][AELEM];
  __shared__ __align__(16) unsigned short sB[2][BELEM];
  const int tid = threadIdx.x;
  const int lane = tid & 63;
  const int wave = tid >> 6;
  const int m0 = blockIdx.x * TM;
  const int n0 = blockIdx.y * TN;

  int a_off[AIT], b_off[BIT], lb[AIT > BIT ? AIT : BIT];
#pragma unroll
  for (int it = 0; it < AIT; it++) {
    int e = it * 2048 + tid * 8;
    int r = e >> 6, cb = (e >> 3) & 7;
    a_off[it] = (m0 + r) * K + ((cb ^ (r & 7)) * 8);
    lb[it] = it * 2048 + wave * 512;
  }
#pragma unroll
  for (int it = 0; it < BIT; it++) {
    int e = it * 2048 + tid * 8;
    int r = e >> 6, cb = (e >> 3) & 7;
    b_off[it] = (n0 + r) * K + ((cb ^ (r & 7)) * 8);
  }

  floatx4 acc[FM][FN];
#pragma unroll
  for (int i = 0; i < FM; i++)
#pragma unroll
    for (int j = 0; j < FN; j++) acc[i][j] = (floatx4){0.f, 0.f, 0.f, 0.f};

  const int nkt = K >> 6;
  const int wm = (wave >> 1) * (TM / 2);
  const int wn = (wave & 1) * (TN / 2);
  const int fr = lane & 15;
  const int q = lane >> 4;

  auto stage = [&](int kt, int buf) {
    const int k0 = kt << 6;
#pragma unroll
    for (int it = 0; it < AIT; it++) async_ld16(A + (size_t)a_off[it] + k0, &sA[buf][lb[it]]);
#pragma unroll
    for (int it = 0; it < BIT; it++) async_ld16(B + (size_t)b_off[it] + k0, &sB[buf][lb[it]]);
  };

  stage(0, 0);
  for (int kt = 0; kt < nkt; kt++) {
    __syncthreads();  // drains stage(kt) (issued one full compute phase ago)
    if (kt + 1 < nkt) stage(kt + 1, (kt + 1) & 1);
    const unsigned short* pA = sA[kt & 1];
    const unsigned short* pB = sB[kt & 1];
#pragma unroll
    for (int kk = 0; kk < 64; kk += 32) {
      short8 af[FM], bfr[FN];
      const int cba = (kk >> 3) + q;
#pragma unroll
      for (int t = 0; t < FM; t++) {
        int ra = wm + t * 16 + fr;
        af[t] = *(const short8*)&pA[ra * 64 + ((cba ^ (ra & 7)) * 8)];
      }
#pragma unroll
      for (int t = 0; t < FN; t++) {
        int rb = wn + t * 16 + fr;
        bfr[t] = *(const short8*)&pB[rb * 64 + ((cba ^ (rb & 7)) * 8)];
      }
#pragma unroll
      for (int i = 0; i < FM; i++)
#pragma unroll
        for (int j = 0; j < FN; j++)
          acc[i][j] = __builtin_amdgcn_mfma_f32_16x16x32_bf16(af[i], bfr[j], acc[i][j], 0, 0, 0);
    }
  }

#pragma unroll
  for (int i = 0; i < FM; i++) {
#pragma unroll
    for (int j = 0; j < FN; j++) {
#pragma unroll
      for (int rg = 0; rg < 4; rg++) {
        int row = m0 + wm + i * 16 + q * 4 + rg;
        int col = n0 + wn + j * 16 + fr;
        float v = acc[i][j][rg];
        if (bias) v += bias[col];
        if (res)  v += res[(size_t)row * N + col];
        if (RELU) v = v > 0.f ? v : 0.f;
        if (OUT_BF16) ((unsigned short*)Cout)[(size_t)row * N + col] = f2bf(v);
        else          ((float*)Cout)[(size_t)row * N + col] = v;
      }
    }
  }
}

// ---------------------------------------------------------------------------
// Embedding gather: x[p,e] = W_in[e, caps[p]] + b_in[e] + pos_emb[p%80, e]
// ---------------------------------------------------------------------------
__global__ __launch_bounds__(512)
void embed_kernel(const int* __restrict__ caps, const float* __restrict__ W_in,
                  const float* __restrict__ b_in, const float* __restrict__ pos,
                  float* __restrict__ x, unsigned short* __restrict__ xbf) {
  int pidx = blockIdx.x;
  int l = pidx % 80;
  int tok = caps[pidx];
  int e = threadIdx.x;
  float v = W_in[(size_t)e * 32000 + tok] + b_in[e] + pos[l * 512 + e];
  x[(size_t)pidx * 512 + e] = v;
  xbf[(size_t)pidx * 512 + e] = f2bf(v);
}

// ---------------------------------------------------------------------------
// Single LayerNorm (for LN3). One wave per row (E=512, 8 vals/lane).
// ---------------------------------------------------------------------------
__global__ __launch_bounds__(256)
void ln_kernel(const float* __restrict__ in, const float* __restrict__ w,
               const float* __restrict__ b, float* __restrict__ xout,
               unsigned short* __restrict__ xbf) {
  int row = blockIdx.x * 4 + (threadIdx.x >> 6);
  int lane = threadIdx.x & 63;
  const float* p = in + (size_t)row * 512;
  float vals[8];
  float s = 0.f, s2 = 0.f;
#pragma unroll
  for (int j = 0; j < 8; j++) {
    float t = p[lane + j * 64];
    vals[j] = t; s += t; s2 += t * t;
  }
#pragma unroll
  for (int off = 32; off; off >>= 1) { s += __shfl_xor(s, off); s2 += __shfl_xor(s2, off); }
  float mean = s * (1.f / 512.f);
  float inv = rsqrtf(s2 * (1.f / 512.f) - mean * mean + 1e-5f);
#pragma unroll
  for (int j = 0; j < 8; j++) {
    int c = lane + j * 64;
    float y = (vals[j] - mean) * inv * w[c] + b[c];
    xout[(size_t)row * 512 + c] = y;
    xbf[(size_t)row * 512 + c] = f2bf(y);
  }
}

// ---------------------------------------------------------------------------
// Fused LN1 -> +cav -> LN2 (saves a kernel + a full x round-trip per layer).
// ---------------------------------------------------------------------------
__global__ __launch_bounds__(256)
void ln2x_kernel(const float* __restrict__ in, const float* __restrict__ cav,
                 const float* __restrict__ w1, const float* __restrict__ b1,
                 const float* __restrict__ w2, const float* __restrict__ b2,
                 float* __restrict__ xout, unsigned short* __restrict__ xbf) {
  int row = blockIdx.x * 4 + (threadIdx.x >> 6);
  int lane = threadIdx.x & 63;
  const float* p = in + (size_t)row * 512;
  float vals[8];
  float s = 0.f, s2 = 0.f;
#pragma unroll
  for (int j = 0; j < 8; j++) {
    float t = p[lane + j * 64];
    vals[j] = t; s += t; s2 += t * t;
  }
#pragma unroll
  for (int off = 32; off; off >>= 1) { s += __shfl_xor(s, off); s2 += __shfl_xor(s2, off); }
  float mean = s * (1.f / 512.f);
  float inv = rsqrtf(s2 * (1.f / 512.f) - mean * mean + 1e-5f);
  float s_b = 0.f, s2_b = 0.f;
#pragma unroll
  for (int j = 0; j < 8; j++) {
    int c = lane + j * 64;
    float y = (vals[j] - mean) * inv * w1[c] + b1[c] + cav[c];
    vals[j] = y; s_b += y; s2_b += y * y;
  }
#pragma unroll
  for (int off = 32; off; off >>= 1) { s_b += __shfl_xor(s_b, off); s2_b += __shfl_xor(s2_b, off); }
  float mean2 = s_b * (1.f / 512.f);
  float inv2 = rsqrtf(s2_b * (1.f / 512.f) - mean2 * mean2 + 1e-5f);
#pragma unroll
  for (int j = 0; j < 8; j++) {
    int c = lane + j * 64;
    float y = (vals[j] - mean2) * inv2 * w2[c] + b2[c];
    xout[(size_t)row * 512 + c] = y;
    xbf[(size_t)row * 512 + c] = f2bf(y);
  }
}

// ---------------------------------------------------------------------------
// MFMA self-attention, one block per (batch, head). L=80, hd=64.
// QK^T: 25 16x16 tiles (K=64); softmax fp32; PV: 20 16x16 tiles (K=96,
// zero-padded). V transposed in LDS; P round-trips LDS bf16 (A-layout).
// ---------------------------------------------------------------------------
__global__ __launch_bounds__(256)
void attn_kernel(const unsigned short* __restrict__ qkv, unsigned short* __restrict__ o) {
  __shared__ __align__(16) unsigned short sq[80][72];
  __shared__ __align__(16) unsigned short sk[80][72];
  __shared__ __align__(16) unsigned short svT[64][96];
  __shared__ __align__(16) unsigned short sp[80][96];
  __shared__ float ss[80][84];
  const int tid = threadIdx.x;
  const int lane = tid & 63;
  const int wave = tid >> 6;
  const int bb = blockIdx.x >> 3, hh = blockIdx.x & 7;
  const unsigned short* base = qkv + (size_t)bb * 80 * 1536 + hh * 64;

  for (int idx = tid; idx < 5120; idx += 256) {
    int r = idx >> 6, c = idx & 63;
    sq[r][c] = base[r * 1536 + c];
    sk[r][c] = base[r * 1536 + 512 + c];
    svT[c][r] = base[r * 1536 + 1024 + c];
  }
  for (int idx = tid; idx < 1024; idx += 256) svT[idx >> 4][80 + (idx & 15)] = 0;
  for (int idx = tid; idx < 1280; idx += 256) sp[idx >> 4][80 + (idx & 15)] = 0;
  __syncthreads();

  const int fr = lane & 15;
  const int q = lane >> 4;

  // S = Q K^T (causal, *0.125)
  for (int t = wave; t < 25; t += 4) {
    int i0 = (t / 5) * 16, j0 = (t % 5) * 16;
    floatx4 acc = (floatx4){0.f, 0.f, 0.f, 0.f};
#pragma unroll
    for (int kk = 0; kk < 64; kk += 32) {
      short8 a = *(const short8*)&sq[i0 + fr][kk + q * 8];
      short8 b = *(const short8*)&sk[j0 + fr][kk + q * 8];
      acc = __builtin_amdgcn_mfma_f32_16x16x32_bf16(a, b, acc, 0, 0, 0);
    }
#pragma unroll
    for (int rg = 0; rg < 4; rg++) {
      int row = i0 + q * 4 + rg, col = j0 + fr;
      ss[row][col] = (col <= row) ? acc[rg] * 0.125f : -1e30f;
    }
  }
  __syncthreads();

  if (tid < 80) {
    float mx = -1e30f;
#pragma unroll
    for (int j = 0; j < 80; j++) mx = fmaxf(mx, ss[tid][j]);
    float sum = 0.f;
#pragma unroll
    for (int j = 0; j < 80; j++) { float e = __expf(ss[tid][j] - mx); ss[tid][j] = e; sum += e; }
    float inv = 1.f / sum;
#pragma unroll
    for (int j = 0; j < 80; j++) sp[tid][j] = f2bf(ss[tid][j] * inv);
  }
  __syncthreads();

  // O = P V  (K = 96, zero-padded)
  for (int t = wave; t < 20; t += 4) {
    int i0 = (t / 4) * 16, d0 = (t % 4) * 16;
    floatx4 acc = (floatx4){0.f, 0.f, 0.f, 0.f};
#pragma unroll
    for (int kk = 0; kk < 96; kk += 32) {
      short8 a = *(const short8*)&sp[i0 + fr][kk + q * 8];
      short8 b = *(const short8*)&svT[d0 + fr][kk + q * 8];
      acc = __builtin_amdgcn_mfma_f32_16x16x32_bf16(a, b, acc, 0, 0, 0);
    }
#pragma unroll
    for (int rg = 0; rg < 4; rg++) {
      int row = i0 + q * 4 + rg;
      o[((size_t)bb * 80 + row) * 512 + hh * 64 + d0 + fr] = f2bf(acc[rg]);
    }
  }
}

// ---------------------------------------------------------------------------
// Cross-attention constants for ALL layers: cav[l,e] = ca_out_b[l,e] +
// sum_f ca_out_w[l,e,f] * ca_in_b[l, 2E+f]   (mem==0, softmax over 1 key)
// ---------------------------------------------------------------------------
__global__ __launch_bounds__(256)
void cavec_kernel(const float* __restrict__ ca_out_w, const float* __restrict__ ca_in_b,
                  const float* __restrict__ ca_out_b, float* __restrict__ cav) {
  int g = blockIdx.x * 4 + (threadIdx.x >> 6);  // 0..2047 = layer*512 + e
  int lane = threadIdx.x & 63;
  int l = g >> 9, e = g & 511;
  const float* row = ca_out_w + ((size_t)l * 512 + e) * 512;
  const float* inb = ca_in_b + l * 1536 + 1024;
  float s = 0.f;
#pragma unroll
  for (int j = 0; j < 8; j++) s += row[lane + j * 64] * inb[lane + j * 64];
#pragma unroll
  for (int off = 32; off; off >>= 1) s += __shfl_xor(s, off);
  if (lane == 0) cav[g] = s + ca_out_b[l * 512 + e];
}

__global__ __launch_bounds__(256)
void convert_f2bf(const float* __restrict__ in, unsigned short* __restrict__ out, int n4) {
  int i = blockIdx.x * 256 + threadIdx.x;
  if (i < n4) {
    float4 v = ((const float4*)in)[i];
    ushort4 r;
    r.x = f2bf(v.x); r.y = f2bf(v.y); r.z = f2bf(v.z); r.w = f2bf(v.w);
    ((ushort4*)out)[i] = r;
  }
}

extern "C" void kernel_launch(void* const* d_in, const int* in_sizes, int n_in,
                              void* d_out, int out_size, void* d_ws, size_t ws_size,
                              hipStream_t stream) {
  const int*   caps     = (const int*)d_in[0];
  const float* W_in     = (const float*)d_in[1];
  const float* b_in     = (const float*)d_in[2];
  const float* pos_emb  = (const float*)d_in[3];
  const float* sa_in_w  = (const float*)d_in[4];
  const float* sa_in_b  = (const float*)d_in[5];
  const float* sa_out_w = (const float*)d_in[6];
  const float* sa_out_b = (const float*)d_in[7];
  const float* ca_in_b  = (const float*)d_in[9];
  const float* ca_out_w = (const float*)d_in[10];
  const float* ca_out_b = (const float*)d_in[11];
  const float* ff1_w    = (const float*)d_in[12];
  const float* ff1_b    = (const float*)d_in[13];
  const float* ff2_w    = (const float*)d_in[14];
  const float* ff2_b    = (const float*)d_in[15];
  const float* ln1_w    = (const float*)d_in[16];
  const float* ln1_b    = (const float*)d_in[17];
  const float* ln2_w    = (const float*)d_in[18];
  const float* ln2_b    = (const float*)d_in[19];
  const float* ln3_w    = (const float*)d_in[20];
  const float* ln3_b    = (const float*)d_in[21];
  const float* out_w    = (const float*)d_in[22];
  const float* out_b    = (const float*)d_in[23];

  char* ws = (char*)d_ws;
  size_t off = 0;
  auto alloc = [&](size_t bytes) {
    void* p = ws + off;
    off += (bytes + 255) & ~(size_t)255;
    return p;
  };
  unsigned short* w_sa_in  = (unsigned short*)alloc((size_t)4 * 1536 * 512 * 2);
  unsigned short* w_sa_out = (unsigned short*)alloc((size_t)4 * 512 * 512 * 2);
  unsigned short* w_ff1    = (unsigned short*)alloc((size_t)4 * 2048 * 512 * 2);
  unsigned short* w_ff2    = (unsigned short*)alloc((size_t)4 * 512 * 2048 * 2);
  unsigned short* w_out    = (unsigned short*)alloc((size_t)32000 * 512 * 2);
  float*          x        = (float*)alloc((size_t)2560 * 512 * 4);
  unsigned short* xbf      = (unsigned short*)alloc((size_t)2560 * 512 * 2);
  float*          t        = (float*)alloc((size_t)2560 * 512 * 4);
  unsigned short* qkv      = (unsigned short*)alloc((size_t)2560 * 1536 * 2);
  unsigned short* obf      = (unsigned short*)alloc((size_t)2560 * 512 * 2);
  unsigned short* hbf      = (unsigned short*)alloc((size_t)2560 * 2048 * 2);
  float*          cav      = (float*)alloc((size_t)2048 * 4);

  convert_f2bf<<<(786432 + 255) / 256, 256, 0, stream>>>(sa_in_w, w_sa_in, 786432);
  convert_f2bf<<<(262144 + 255) / 256, 256, 0, stream>>>(sa_out_w, w_sa_out, 262144);
  convert_f2bf<<<(1048576 + 255) / 256, 256, 0, stream>>>(ff1_w, w_ff1, 1048576);
  convert_f2bf<<<(1048576 + 255) / 256, 256, 0, stream>>>(ff2_w, w_ff2, 1048576);
  convert_f2bf<<<(4096000 + 255) / 256, 256, 0, stream>>>(out_w, w_out, 4096000);

  embed_kernel<<<2560, 512, 0, stream>>>(caps, W_in, b_in, pos_emb, x, xbf);
  cavec_kernel<<<512, 256, 0, stream>>>(ca_out_w, ca_in_b, ca_out_b, cav);

  for (int i = 0; i < 4; i++) {
    gemm_bt<128, 128, 1, 0><<<dim3(20, 12), 256, 0, stream>>>(
        xbf, w_sa_in + (size_t)i * 1536 * 512, sa_in_b + i * 1536, nullptr,
        qkv, 2560, 1536, 512);
    attn_kernel<<<256, 256, 0, stream>>>(qkv, obf);
    gemm_bt<64, 64, 0, 0><<<dim3(40, 8), 256, 0, stream>>>(
        obf, w_sa_out + (size_t)i * 512 * 512, sa_out_b + i * 512, x,
        t, 2560, 512, 512);
    ln2x_kernel<<<640, 256, 0, stream>>>(t, cav + i * 512,
        ln1_w + i * 512, ln1_b + i * 512, ln2_w + i * 512, ln2_b + i * 512, x, xbf);
    gemm_bt<128, 128, 1, 1><<<dim3(20, 16), 256, 0, stream>>>(
        xbf, w_ff1 + (size_t)i * 2048 * 512, ff1_b + i * 2048, nullptr,
        hbf, 2560, 2048, 512);
    gemm_bt<64, 64, 0, 0><<<dim3(40, 8), 256, 0, stream>>>(
        hbf, w_ff2 + (size_t)i * 512 * 2048, ff2_b + i * 512, x,
        t, 2560, 512, 2048);
    ln_kernel<<<640, 256, 0, stream>>>(t, ln3_w + i * 512, ln3_b + i * 512, x, xbf);
  }

  gemm_bt<128, 128, 0, 0><<<dim3(20, 250), 256, 0, stream>>>(
      xbf, w_out, out_b, nullptr, (float*)d_out, 2560, 32000, 512);
}